// Round 1
// 732.207 us; speedup vs baseline: 1.0015x; 1.0015x over previous
//
#include <hip/hip_runtime.h>
#include <hip/hip_bf16.h>

// Problem constants (reference: R=8, N=4096, IN_F=OUT_F=64)
#define RR 8
#define NN 4096
#define FF 64

typedef float f32x4 __attribute__((ext_vector_type(4)));
typedef short bf16x8 __attribute__((ext_vector_type(8)));

__device__ __forceinline__ short f2b(float f) {
  __hip_bfloat16 h = __float2bfloat16(f);
  return __builtin_bit_cast(short, h);
}

__device__ __forceinline__ bf16x8 cvt8(f32x4 lo, f32x4 hi) {
  bf16x8 r;
  r[0] = f2b(lo[0]); r[1] = f2b(lo[1]); r[2] = f2b(lo[2]); r[3] = f2b(lo[3]);
  r[4] = f2b(hi[0]); r[5] = f2b(hi[1]); r[6] = f2b(hi[2]); r[7] = f2b(hi[3]);
  return r;
}

// ---------------------------------------------------------------------------
// Kernel 1: Zt[r][o][m] = sum_i W[r][o][i] * x[m][i], stored bf16 in d_ws.
// (unchanged — verified correct)
__global__ __launch_bounds__(256) void compute_zt(const float* __restrict__ x,
                                                  const float* __restrict__ w,
                                                  short* __restrict__ zt) {
  const int tid   = threadIdx.x;
  const int lane  = tid & 63;
  const int wv    = tid >> 6;
  const int row16 = lane & 15;
  const int quad  = lane >> 4;
  const int r     = blockIdx.y;
  const int m0    = blockIdx.x * 64 + wv * 16;

  bf16x8 bfr[2];
#pragma unroll
  for (int s = 0; s < 2; ++s) {
    const float* p = x + (size_t)(m0 + row16) * FF + s * 32 + quad * 8;
    bfr[s] = cvt8(*(const f32x4*)p, *(const f32x4*)(p + 4));
  }

  f32x4 acc[4] = {{0.f,0.f,0.f,0.f},{0.f,0.f,0.f,0.f},
                  {0.f,0.f,0.f,0.f},{0.f,0.f,0.f,0.f}};
#pragma unroll
  for (int og = 0; og < 4; ++og) {
#pragma unroll
    for (int s = 0; s < 2; ++s) {
      const float* p = w + ((size_t)r * FF + og * 16 + row16) * FF + s * 32 + quad * 8;
      bf16x8 afr = cvt8(*(const f32x4*)p, *(const f32x4*)(p + 4));
      acc[og] = __builtin_amdgcn_mfma_f32_16x16x32_bf16(afr, bfr[s], acc[og], 0, 0, 0);
    }
  }

#pragma unroll
  for (int og = 0; og < 4; ++og)
#pragma unroll
    for (int j = 0; j < 4; ++j) {
      int o = og * 16 + quad * 4 + j;
      int m = m0 + row16;
      zt[((size_t)r * FF + o) * NN + m] = f2b(acc[og][j]);
    }
}

// ---------------------------------------------------------------------------
// Kernel 2: partial[rk][n][o] = sum_{m in half} A[r][n][m] * Zt[r][o][m]
// grid = (64 row-tiles, 16 = r*2 + khalf), block 256 = 4 waves x 16 rows.
//
// Pipeline (R0 fix): the old loop issued A(s+2) immediately BEFORE
// __syncthreads(); hipcc emits s_waitcnt vmcnt(0) before s_barrier, so every
// stage drained its freshly-issued A-loads at full HBM latency with all 4
// waves blocked (prefetch distance collapsed to 0 -> ~1.6 TB/s A-stream).
// New order per stage s:
//   [barrier from s-1]
//   (1) all 16 B-loads for stage s        (oldest in vmcnt queue)
//   (2) 8 A-loads for stage s+1           (younger: MFMA waits on B do NOT
//                                          transitively retire A)
//   (3) ds_read A-frags + 16 MFMA         (hides A's HBM latency)
//   (4) writeA buf[(s+1)&1]               (vmcnt wait for A lands here,
//                                          after a full stage of compute)
//   (5) __syncthreads()                   (vmcnt already 0 -> no drain stall)
// sched_barrier(0) pins the B-before-A issue order against the scheduler.
// Accumulation order identical to previous version -> bitwise-same output.

#define BK    128                 // k-floats per stage
#define NSTG  16                  // 2048 / BK
#define LROW  136                 // LDS row stride in shorts (128 + 8 pad)

__device__ __forceinline__ void issueA(const float* __restrict__ abase,
                                       int trow, int tcol, int s, f32x4* av) {
#pragma unroll
  for (int i = 0; i < 8; ++i)
    av[i] = *(const f32x4*)(abase + (size_t)(i * 8 + trow) * NN + s * BK + tcol);
}

__device__ __forceinline__ void writeA(short* __restrict__ buf,
                                       int trow, int tcol, const f32x4* av) {
#pragma unroll
  for (int i = 0; i < 8; ++i) {
    short4 wv4;
    wv4.x = f2b(av[i][0]); wv4.y = f2b(av[i][1]);
    wv4.z = f2b(av[i][2]); wv4.w = f2b(av[i][3]);
    *(short4*)(buf + (i * 8 + trow) * LROW + tcol) = wv4;
  }
}

__device__ __forceinline__ void loadB4(const short* __restrict__ zb, int k, bf16x8* b) {
#pragma unroll
  for (int cg = 0; cg < 4; ++cg)
    b[cg] = *(const bf16x8*)(zb + (size_t)cg * 16 * NN + k);
}

__device__ __forceinline__ void mfma4(bf16x8 a, const bf16x8* b, f32x4* acc) {
  acc[0] = __builtin_amdgcn_mfma_f32_16x16x32_bf16(a, b[0], acc[0], 0, 0, 0);
  acc[1] = __builtin_amdgcn_mfma_f32_16x16x32_bf16(a, b[1], acc[1], 0, 0, 0);
  acc[2] = __builtin_amdgcn_mfma_f32_16x16x32_bf16(a, b[2], acc[2], 0, 0, 0);
  acc[3] = __builtin_amdgcn_mfma_f32_16x16x32_bf16(a, b[3], acc[3], 0, 0, 0);
}

__global__ __launch_bounds__(256, 3) void rgcn_main(const float* __restrict__ adj,
                                                    const short* __restrict__ zt,
                                                    float* __restrict__ partial) {
  __shared__ short lds[2][64 * LROW];   // 2 x 17 KiB

  const int tid   = threadIdx.x;
  const int lane  = tid & 63;
  const int wv    = tid >> 6;
  const int row16 = lane & 15;
  const int quad  = lane >> 4;

  const int nt   = blockIdx.x;
  const int rk   = blockIdx.y;
  const int r    = rk >> 1;
  const int half = rk & 1;
  const int n0   = nt * 64;

  // Cooperative A-staging mapping: thread t, instr i reads
  // row = i*8 + (t>>5), floats [ (t&31)*4 , +4 ) of the 128-float stage chunk.
  // => each wave-instruction = 2 rows x 512B fully contiguous, lane-ordered.
  const int trow = tid >> 5;          // 0..7
  const int tcol = (tid & 31) * 4;    // 0..124

  const float* abase = adj + (size_t)r * NN * NN + (size_t)n0 * NN + half * 2048;
  const short* zb    = zt + (size_t)r * FF * NN + (size_t)row16 * NN
                          + half * 2048 + quad * 8;

  f32x4 acc[4] = {{0.f,0.f,0.f,0.f},{0.f,0.f,0.f,0.f},
                  {0.f,0.f,0.f,0.f},{0.f,0.f,0.f,0.f}};
  f32x4 av[8];

  // Prologue: stage 0 -> LDS buf0 (one exposed HBM round-trip, once).
  issueA(abase, trow, tcol, 0, av);
  writeA(&lds[0][0], trow, tcol, av);
  __syncthreads();

#pragma unroll 1
  for (int s = 0; s < NSTG; ++s) {
    const short* fb = &lds[s & 1][(wv * 16 + row16) * LROW + quad * 8];

    // (1) B-loads for this stage — issued FIRST so they are the oldest
    //     entries in the vmcnt queue (zt is L2-resident, ~200cy).
    bf16x8 b0[4], b1[4], b2[4], b3[4];
    loadB4(zb, s * BK,      b0);
    loadB4(zb, s * BK + 32, b1);
    loadB4(zb, s * BK + 64, b2);
    loadB4(zb, s * BK + 96, b3);
    __builtin_amdgcn_sched_barrier(0);

    // (2) A-prefetch for stage s+1 — younger than all B-loads, so the
    //     compiler's vmcnt waits before each MFMA retire only B.
    if (s < NSTG - 1) issueA(abase, trow, tcol, s + 1, av);
    __builtin_amdgcn_sched_barrier(0);

    // (3) compute stage s from LDS; A(s+1) in flight underneath.
    bf16x8 a0 = *(const bf16x8*)(fb + 0);
    mfma4(a0, b0, acc);
    bf16x8 a1 = *(const bf16x8*)(fb + 32);
    mfma4(a1, b1, acc);
    bf16x8 a2 = *(const bf16x8*)(fb + 64);
    mfma4(a2, b2, acc);
    bf16x8 a3 = *(const bf16x8*)(fb + 96);
    mfma4(a3, b3, acc);

    // (4)+(5) consume A(s+1) into the other LDS buffer, then barrier.
    // vmcnt wait happens at writeA (after a full stage of compute); by the
    // barrier nothing is outstanding, so its mandatory vmcnt(0) is free.
    if (s < NSTG - 1) {
      writeA(&lds[(s + 1) & 1][0], trow, tcol, av);
      __syncthreads();
    }
  }

  // Epilogue: plain stores of this block's partial tile.
  float* pb = partial + ((size_t)rk * NN + n0) * FF;
#pragma unroll
  for (int cg = 0; cg < 4; ++cg)
#pragma unroll
    for (int j = 0; j < 4; ++j)
      pb[(size_t)(wv * 16 + quad * 4 + j) * FF + cg * 16 + row16] = acc[cg][j];
}

// ---------------------------------------------------------------------------
// Kernel 3: out[n][o] = sum_{rk=0..15} partial[rk][n][o]   (f32x4 vectorized)
__global__ __launch_bounds__(256) void reduce_partials(const f32x4* __restrict__ p,
                                                       f32x4* __restrict__ out) {
  const int idx = blockIdx.x * 256 + threadIdx.x;   // 65536 f32x4 elements
  f32x4 s = {0.f, 0.f, 0.f, 0.f};
#pragma unroll
  for (int rk = 0; rk < 16; ++rk)
    s += p[(size_t)rk * (NN * FF / 4) + idx];
  out[idx] = s;
}

// ---------------------------------------------------------------------------
extern "C" void kernel_launch(void* const* d_in, const int* in_sizes, int n_in,
                              void* d_out, int out_size, void* d_ws, size_t ws_size,
                              hipStream_t stream) {
  const float* adj = (const float*)d_in[0];   // [8, 4096, 4096] fp32
  const float* x   = (const float*)d_in[1];   // [4096, 64] fp32
  const float* w   = (const float*)d_in[2];   // [8, 64, 64] fp32
  float* out = (float*)d_out;                 // [4096, 64] fp32

  short* zt      = (short*)d_ws;                            // 4 MiB
  float* partial = (float*)((char*)d_ws + (16u << 20));     // 16 MiB @ +16 MiB

  compute_zt<<<dim3(NN / 64, RR), 256, 0, stream>>>(x, w, zt);
  rgcn_main<<<dim3(NN / 64, RR * 2), 256, 0, stream>>>(adj, zt, partial);
  reduce_partials<<<dim3(NN * FF / 4 / 256), 256, 0, stream>>>(
      (const f32x4*)partial, (f32x4*)out);
}

// Round 2
// 724.982 us; speedup vs baseline: 1.0115x; 1.0100x over previous
//
#include <hip/hip_runtime.h>
#include <hip/hip_bf16.h>

// Problem constants (reference: R=8, N=4096, IN_F=OUT_F=64)
#define RR 8
#define NN 4096
#define FF 64

typedef float f32x4 __attribute__((ext_vector_type(4)));
typedef short bf16x8 __attribute__((ext_vector_type(8)));

__device__ __forceinline__ short f2b(float f) {
  __hip_bfloat16 h = __float2bfloat16(f);
  return __builtin_bit_cast(short, h);
}

__device__ __forceinline__ bf16x8 cvt8(f32x4 lo, f32x4 hi) {
  bf16x8 r;
  r[0] = f2b(lo[0]); r[1] = f2b(lo[1]); r[2] = f2b(lo[2]); r[3] = f2b(lo[3]);
  r[4] = f2b(hi[0]); r[5] = f2b(hi[1]); r[6] = f2b(hi[2]); r[7] = f2b(hi[3]);
  return r;
}

// ---------------------------------------------------------------------------
// Kernel 1: Zt[r][o][m] = sum_i W[r][o][i] * x[m][i], stored bf16 in d_ws.
// (unchanged — verified correct)
__global__ __launch_bounds__(256) void compute_zt(const float* __restrict__ x,
                                                  const float* __restrict__ w,
                                                  short* __restrict__ zt) {
  const int tid   = threadIdx.x;
  const int lane  = tid & 63;
  const int wv    = tid >> 6;
  const int row16 = lane & 15;
  const int quad  = lane >> 4;
  const int r     = blockIdx.y;
  const int m0    = blockIdx.x * 64 + wv * 16;

  bf16x8 bfr[2];
#pragma unroll
  for (int s = 0; s < 2; ++s) {
    const float* p = x + (size_t)(m0 + row16) * FF + s * 32 + quad * 8;
    bfr[s] = cvt8(*(const f32x4*)p, *(const f32x4*)(p + 4));
  }

  f32x4 acc[4] = {{0.f,0.f,0.f,0.f},{0.f,0.f,0.f,0.f},
                  {0.f,0.f,0.f,0.f},{0.f,0.f,0.f,0.f}};
#pragma unroll
  for (int og = 0; og < 4; ++og) {
#pragma unroll
    for (int s = 0; s < 2; ++s) {
      const float* p = w + ((size_t)r * FF + og * 16 + row16) * FF + s * 32 + quad * 8;
      bf16x8 afr = cvt8(*(const f32x4*)p, *(const f32x4*)(p + 4));
      acc[og] = __builtin_amdgcn_mfma_f32_16x16x32_bf16(afr, bfr[s], acc[og], 0, 0, 0);
    }
  }

#pragma unroll
  for (int og = 0; og < 4; ++og)
#pragma unroll
    for (int j = 0; j < 4; ++j) {
      int o = og * 16 + quad * 4 + j;
      int m = m0 + row16;
      zt[((size_t)r * FF + o) * NN + m] = f2b(acc[og][j]);
    }
}

// ---------------------------------------------------------------------------
// Kernel 2: partial[rk][n][o] = sum_{m in half} A[r][n][m] * Zt[r][o][m]
// grid = 1024 blocks (1-D), block 256 = 4 waves x 16 rows.
//
// R2 change — XCD-aware work assignment. Old grid (64,16) gave
// XCD = (x + 64*y) % 8 = x % 8: every XCD ran all 8 relations, so its 4 MiB
// L2 had to hold the ENTIRE 4 MiB zt while 537 MB of A streamed through it.
// zt was continuously evicted; the 4x wave-redundant B-loads (1 GB total)
// fell through to HBM -> kernel ran ~3.5x over the A-stream roofline and was
// insensitive to pipeline reshuffles (R0/R1 null results).
// With round-robin dispatch XCD = bid % 8, we take r = bid & 7: each XCD
// owns exactly ONE relation -> zt working set 512 KB, L2-resident under the
// A stream. B-loads become L2 hits; HBM traffic drops to ~A only.
// Pure permutation of block->work mapping: bitwise-identical output.

#define BK    128                 // k-floats per stage
#define NSTG  16                  // 2048 / BK
#define LROW  136                 // LDS row stride in shorts (128 + 8 pad)

__device__ __forceinline__ void issueA(const float* __restrict__ abase,
                                       int trow, int tcol, int s, f32x4* av) {
#pragma unroll
  for (int i = 0; i < 8; ++i)
    av[i] = *(const f32x4*)(abase + (size_t)(i * 8 + trow) * NN + s * BK + tcol);
}

__device__ __forceinline__ void writeA(short* __restrict__ buf,
                                       int trow, int tcol, const f32x4* av) {
#pragma unroll
  for (int i = 0; i < 8; ++i) {
    short4 wv4;
    wv4.x = f2b(av[i][0]); wv4.y = f2b(av[i][1]);
    wv4.z = f2b(av[i][2]); wv4.w = f2b(av[i][3]);
    *(short4*)(buf + (i * 8 + trow) * LROW + tcol) = wv4;
  }
}

__device__ __forceinline__ void loadB4(const short* __restrict__ zb, int k, bf16x8* b) {
#pragma unroll
  for (int cg = 0; cg < 4; ++cg)
    b[cg] = *(const bf16x8*)(zb + (size_t)cg * 16 * NN + k);
}

__device__ __forceinline__ void mfma4(bf16x8 a, const bf16x8* b, f32x4* acc) {
  acc[0] = __builtin_amdgcn_mfma_f32_16x16x32_bf16(a, b[0], acc[0], 0, 0, 0);
  acc[1] = __builtin_amdgcn_mfma_f32_16x16x32_bf16(a, b[1], acc[1], 0, 0, 0);
  acc[2] = __builtin_amdgcn_mfma_f32_16x16x32_bf16(a, b[2], acc[2], 0, 0, 0);
  acc[3] = __builtin_amdgcn_mfma_f32_16x16x32_bf16(a, b[3], acc[3], 0, 0, 0);
}

__global__ __launch_bounds__(256, 3) void rgcn_main(const float* __restrict__ adj,
                                                    const short* __restrict__ zt,
                                                    float* __restrict__ partial) {
  __shared__ short lds[2][64 * LROW];   // 2 x 17 KiB

  const int tid   = threadIdx.x;
  const int lane  = tid & 63;
  const int wv    = tid >> 6;
  const int row16 = lane & 15;
  const int quad  = lane >> 4;

  // XCD-aware de-interleave (round-robin dispatch: XCD = blockIdx.x % 8).
  // XCD k gets only relation r=k -> 512 KB zt working set per L2.
  const int bid  = blockIdx.x;          // 0..1023
  const int r    = bid & 7;             // relation == XCD id
  const int idx  = bid >> 3;            // 0..127
  const int half = idx & 1;
  const int nt   = idx >> 1;            // 0..63
  const int rk   = r * 2 + half;
  const int n0   = nt * 64;

  // Cooperative A-staging mapping: thread t, instr i reads
  // row = i*8 + (t>>5), floats [ (t&31)*4 , +4 ) of the 128-float stage chunk.
  // => each wave-instruction = 2 rows x 512B fully contiguous, lane-ordered.
  const int trow = tid >> 5;          // 0..7
  const int tcol = (tid & 31) * 4;    // 0..124

  const float* abase = adj + (size_t)r * NN * NN + (size_t)n0 * NN + half * 2048;
  const short* zb    = zt + (size_t)r * FF * NN + (size_t)row16 * NN
                          + half * 2048 + quad * 8;

  f32x4 acc[4] = {{0.f,0.f,0.f,0.f},{0.f,0.f,0.f,0.f},
                  {0.f,0.f,0.f,0.f},{0.f,0.f,0.f,0.f}};
  f32x4 av[8];

  // Prologue: stage 0 -> LDS buf0 (one exposed HBM round-trip, once).
  issueA(abase, trow, tcol, 0, av);
  writeA(&lds[0][0], trow, tcol, av);
  __syncthreads();

#pragma unroll 1
  for (int s = 0; s < NSTG; ++s) {
    const short* fb = &lds[s & 1][(wv * 16 + row16) * LROW + quad * 8];

    // (1) B-loads for this stage — L2-resident zt after the XCD remap.
    bf16x8 b0[4], b1[4], b2[4], b3[4];
    loadB4(zb, s * BK,      b0);
    loadB4(zb, s * BK + 32, b1);
    loadB4(zb, s * BK + 64, b2);
    loadB4(zb, s * BK + 96, b3);
    __builtin_amdgcn_sched_barrier(0);

    // (2) A-prefetch for stage s+1.
    if (s < NSTG - 1) issueA(abase, trow, tcol, s + 1, av);
    __builtin_amdgcn_sched_barrier(0);

    // (3) compute stage s from LDS; A(s+1) in flight underneath.
    bf16x8 a0 = *(const bf16x8*)(fb + 0);
    mfma4(a0, b0, acc);
    bf16x8 a1 = *(const bf16x8*)(fb + 32);
    mfma4(a1, b1, acc);
    bf16x8 a2 = *(const bf16x8*)(fb + 64);
    mfma4(a2, b2, acc);
    bf16x8 a3 = *(const bf16x8*)(fb + 96);
    mfma4(a3, b3, acc);

    // (4)+(5) consume A(s+1) into the other LDS buffer, then barrier.
    if (s < NSTG - 1) {
      writeA(&lds[(s + 1) & 1][0], trow, tcol, av);
      __syncthreads();
    }
  }

  // Epilogue: plain stores of this block's partial tile.
  float* pb = partial + ((size_t)rk * NN + n0) * FF;
#pragma unroll
  for (int cg = 0; cg < 4; ++cg)
#pragma unroll
    for (int j = 0; j < 4; ++j)
      pb[(size_t)(wv * 16 + quad * 4 + j) * FF + cg * 16 + row16] = acc[cg][j];
}

// ---------------------------------------------------------------------------
// Kernel 3: out[n][o] = sum_{rk=0..15} partial[rk][n][o]   (f32x4 vectorized)
__global__ __launch_bounds__(256) void reduce_partials(const f32x4* __restrict__ p,
                                                       f32x4* __restrict__ out) {
  const int idx = blockIdx.x * 256 + threadIdx.x;   // 65536 f32x4 elements
  f32x4 s = {0.f, 0.f, 0.f, 0.f};
#pragma unroll
  for (int rk = 0; rk < 16; ++rk)
    s += p[(size_t)rk * (NN * FF / 4) + idx];
  out[idx] = s;
}

// ---------------------------------------------------------------------------
extern "C" void kernel_launch(void* const* d_in, const int* in_sizes, int n_in,
                              void* d_out, int out_size, void* d_ws, size_t ws_size,
                              hipStream_t stream) {
  const float* adj = (const float*)d_in[0];   // [8, 4096, 4096] fp32
  const float* x   = (const float*)d_in[1];   // [4096, 64] fp32
  const float* w   = (const float*)d_in[2];   // [8, 64, 64] fp32
  float* out = (float*)d_out;                 // [4096, 64] fp32

  short* zt      = (short*)d_ws;                            // 4 MiB
  float* partial = (float*)((char*)d_ws + (16u << 20));     // 16 MiB @ +16 MiB

  compute_zt<<<dim3(NN / 64, RR), 256, 0, stream>>>(x, w, zt);
  rgcn_main<<<dim3(1024), 256, 0, stream>>>(adj, zt, partial);
  reduce_partials<<<dim3(NN * FF / 4 / 256), 256, 0, stream>>>(
      (const f32x4*)partial, (f32x4*)out);
}